// Round 2
// baseline (210.419 us; speedup 1.0000x reference)
//
#include <hip/hip_runtime.h>
#include <hip/hip_bf16.h>

#define B_DIM 8
#define C_DIM 256
#define S_DIM 2304

// srcT/dstT layout: MFMA-fragment-tiled  [B][S/16][C/8][16 rows][8 k]
//   T(s,c) = (s>>4)*4096 + (c>>3)*128 + (s&15)*8 + (c&7)      (elems)
// A wave's A/B fragment load for mfma_16x16x32_bf16 (rows r0+{0..15},
// k = ki*32 + (lane>>4)*8 + {0..7}) becomes base + lane*16B -> one fully
// coalesced 1 KB global_load_dwordx4 straight from the XCD-resident L2
// (2.36 MB per batch << 4 MB). This deletes the entire main-loop LDS
// stage + all 16 per-block barriers of the previous structure.

typedef __attribute__((ext_vector_type(8))) short short8;
typedef __attribute__((ext_vector_type(4))) float floatx4;

// ---------------------------------------------------------------------------
// Kernel 1: per-(b,s) L2-normalize over C, f32 [B,C,S] -> bf16 tiled layout.
// Only the write-out mapping changed vs the verified version; LDS read side
// stays 2-way-conflict-free (row stride 264 elems, banks 4*(fm+cg) mod 32).
// ---------------------------------------------------------------------------
__global__ __launch_bounds__(256) void norm_transpose_kernel(
    const float* __restrict__ src, const float* __restrict__ dst,
    __hip_bfloat16* __restrict__ srcT, __hip_bfloat16* __restrict__ dstT) {
    const int s0 = blockIdx.x * 64;
    const int b  = blockIdx.y;
    const float* in = (blockIdx.z == 0 ? src : dst) + (size_t)b * C_DIM * S_DIM;
    __hip_bfloat16* out = (blockIdx.z == 0 ? srcT : dstT) + (size_t)b * S_DIM * C_DIM;

    __shared__ __align__(16) __hip_bfloat16 tile[64][C_DIM + 8];
    __shared__ float red[4][64];
    __shared__ float invn[64];

    const int t  = threadIdx.x;
    const int l  = t & 63;
    const int wv = t >> 6;

    float ss = 0.f;
#pragma unroll 8
    for (int c = wv; c < C_DIM; c += 4) {
        float v = in[(size_t)c * S_DIM + s0 + l];
        ss += v * v;
        tile[l][c] = __float2bfloat16(v);
    }
    red[wv][l] = ss;
    __syncthreads();
    if (t < 64) invn[t] = rsqrtf(red[0][t] + red[1][t] + red[2][t] + red[3][t]);
    __syncthreads();

    // Emit tiled layout. Per 16-lane group the 16 B stores are contiguous
    // (stride 8 elems in fm) -> 1 KB contiguous per wave.
#pragma unroll
    for (int it = 0; it < 8; ++it) {
        int gidx = it * 256 + t;
        int fm   = gidx & 15;          // row within 16-group
        int cg   = (gidx >> 4) & 31;   // k-chunk (8 bf16)
        int sg   = gidx >> 9;          // row-group within block (0..3)
        int srow = sg * 16 + fm;
        float inv = invn[srow];
        union { short8 v; __hip_bfloat16 h[8]; } u, o;
        u.v = *(const short8*)&tile[srow][cg * 8];
#pragma unroll
        for (int j = 0; j < 8; ++j)
            o.h[j] = __float2bfloat16(__bfloat162float(u.h[j]) * inv);
        *(short8*)&out[(size_t)((s0 >> 4) + sg) * 4096 + cg * 128 + fm * 8] = o.v;
    }
}

// ---------------------------------------------------------------------------
// Kernel 2: per-batch GEMM  out[b][m][n] = relu( sum_k A[m][k]*B[n][k] )
// LDS-free main loop: fragments stream directly from L2 via perfectly
// coalesced 1 KB loads (tiled layout above), ping-pong double-buffered in
// registers. No barriers until the epilogue. Batch->XCD swizzle keeps each
// batch's 2.36 MB of A+B hot in one XCD's L2 across its 324 blocks.
// VGPR budget: acc 64 + 4x frag-set 64 + addr ~ <=170 -> 3 waves/SIMD
// (enforced by __launch_bounds__(256,3)).
// Epilogue: verified Cs-transpose path (banks 2-way = free), ReLU fused.
// ---------------------------------------------------------------------------
__global__ __launch_bounds__(256, 3) void gemm_relu_kernel(
    const __hip_bfloat16* __restrict__ At, const __hip_bfloat16* __restrict__ Bt,
    float* __restrict__ out) {
    const int id = blockIdx.x;
    const int b  = id & 7;          // batch -> XCD (id%8 round-robin)
    const int q  = id >> 3;
    const int m0 = (q % 18) * 128;
    const int n0 = (q / 18) * 128;

    __shared__ __align__(16) float Cs[64 * 132];

    const int t    = threadIdx.x;
    const int lane = t & 63;
    const int wv   = t >> 6;

    const int fm = lane & 15;
    const int wr = (wv >> 1) << 6;
    const int wc = (wv & 1) << 6;
    const int rq = (lane >> 4) << 2;

    // Per-lane fragment base: tiled layout makes this base + lane*16B.
    const __hip_bfloat16* pA = At + (size_t)b * S_DIM * C_DIM
                             + (size_t)((m0 + wr) >> 4) * 4096 + lane * 8;
    const __hip_bfloat16* pB = Bt + (size_t)b * S_DIM * C_DIM
                             + (size_t)((n0 + wc) >> 4) * 4096 + lane * 8;
    // frag i: +i*4096 (next 16-row group); k-iter ki: +ki*512 (4 k-chunks)

    floatx4 acc[4][4] = {};
    short8 a0[4], b0[4], a1[4], b1[4];

#pragma unroll
    for (int i = 0; i < 4; ++i) {
        a0[i] = *(const short8*)(pA + i * 4096);
        b0[i] = *(const short8*)(pB + i * 4096);
    }

#pragma unroll
    for (int ki = 0; ki < 8; ki += 2) {
        // prefetch iter ki+1 while computing iter ki
#pragma unroll
        for (int i = 0; i < 4; ++i) {
            a1[i] = *(const short8*)(pA + i * 4096 + (ki + 1) * 512);
            b1[i] = *(const short8*)(pB + i * 4096 + (ki + 1) * 512);
        }
        __builtin_amdgcn_s_setprio(1);
#pragma unroll
        for (int i = 0; i < 4; ++i)
#pragma unroll
            for (int j = 0; j < 4; ++j)
                acc[i][j] = __builtin_amdgcn_mfma_f32_16x16x32_bf16(a0[i], b0[j], acc[i][j], 0, 0, 0);
        __builtin_amdgcn_s_setprio(0);

        if (ki + 2 < 8) {
#pragma unroll
            for (int i = 0; i < 4; ++i) {
                a0[i] = *(const short8*)(pA + i * 4096 + (ki + 2) * 512);
                b0[i] = *(const short8*)(pB + i * 4096 + (ki + 2) * 512);
            }
        }
        __builtin_amdgcn_s_setprio(1);
#pragma unroll
        for (int i = 0; i < 4; ++i)
#pragma unroll
            for (int j = 0; j < 4; ++j)
                acc[i][j] = __builtin_amdgcn_mfma_f32_16x16x32_bf16(a1[i], b1[j], acc[i][j], 0, 0, 0);
        __builtin_amdgcn_s_setprio(0);
    }

    // Epilogue: acc -> padded LDS f32 tile -> coalesced float4 stores, ReLU fused.
    float* Cp = out + (size_t)b * S_DIM * S_DIM;
#pragma unroll
    for (int p = 0; p < 2; ++p) {
        __syncthreads();   // prior Cs reads done (and wave convergence on p=0)
#pragma unroll
        for (int i2 = 0; i2 < 2; ++i2) {
            int i = 2 * p + i2;
            int slot = (wr >> 1) + i2 * 16 + rq;
#pragma unroll
            for (int j = 0; j < 4; ++j) {
                int col = wc + j * 16 + fm;
#pragma unroll
                for (int r = 0; r < 4; ++r)
                    Cs[(slot + r) * 132 + col] = fmaxf(acc[i][j][r], 0.f);
            }
        }
        __syncthreads();
#pragma unroll
        for (int it = 0; it < 8; ++it) {
            int idx  = it * 256 + t;
            int srow = idx >> 5;
            int c4   = (idx & 31) << 2;
            float4 v = *(const float4*)&Cs[srow * 132 + c4];
            int lrow = 32 * p + (srow & 31) + ((srow >> 5) << 6);
            *(float4*)&Cp[(size_t)(m0 + lrow) * S_DIM + n0 + c4] = v;
        }
    }
}

extern "C" void kernel_launch(void* const* d_in, const int* in_sizes, int n_in,
                              void* d_out, int out_size, void* d_ws, size_t ws_size,
                              hipStream_t stream) {
    const float* src = (const float*)d_in[0];
    const float* dst = (const float*)d_in[1];
    float* out = (float*)d_out;

    __hip_bfloat16* srcT = (__hip_bfloat16*)d_ws;
    __hip_bfloat16* dstT = srcT + (size_t)B_DIM * S_DIM * C_DIM;

    dim3 g1(S_DIM / 64, B_DIM, 2);
    norm_transpose_kernel<<<g1, 256, 0, stream>>>(src, dst, srcT, dstT);

    gemm_relu_kernel<<<dim3(B_DIM * 18 * 18), 256, 0, stream>>>(srcT, dstT, out);
}